// Round 8
// baseline (1034.242 us; speedup 1.0000x reference)
//
#include <hip/hip_runtime.h>
#include <math.h>

#define NN 50000
#define NE 800000
#define NEG_SLOPE 0.2f
#define LN_EPS 1e-5f
#define SROW 264  // LDS stage row stride in ushorts (256 + 8 pad)

typedef unsigned short ushort_t;
typedef unsigned int uint_t;
typedef __attribute__((ext_vector_type(8))) short bf16x8;
typedef __attribute__((ext_vector_type(4))) float f32x4;

__device__ __forceinline__ float bf2f(ushort_t u) {
    return __uint_as_float(((uint_t)u) << 16);
}
__device__ __forceinline__ ushort_t f2bf(float f) {
    uint_t b = __float_as_uint(f);
    uint_t r = (b + 0x7fffu + ((b >> 16) & 1u)) >> 16;
    return (ushort_t)r;
}
// generic float-input load: isbf ? bf16[i] : f32[i]
__device__ __forceinline__ float ldx(const void* p, size_t i, int isbf) {
    return isbf ? bf2f(((const ushort_t*)p)[i]) : ((const float*)p)[i];
}
__device__ __forceinline__ int clampN(int v) {
    return v < 0 ? 0 : (v >= NN ? NN - 1 : v);
}
// edge-index loads, robust to int64 storage (low word holds value)
__device__ __forceinline__ int ld_src(const int* ei, int e, int f64) {
    return clampN(f64 ? ei[2 * e] : ei[e]);
}
__device__ __forceinline__ int ld_dst(const int* ei, int e, int f64) {
    return clampN(f64 ? ei[2 * NE + 2 * e] : ei[NE + e]);
}

// flags[0] = edge_index-is-int64, flags[1] = floats-are-bf16
__global__ void detect_flags(const int* __restrict__ ei, const void* __restrict__ hptr,
                             int* __restrict__ flags) {
    if (threadIdx.x != 0) return;
    flags[0] = (ei[1] == 0 && ei[3] == 0 && ei[5] == 0 && ei[7] == 0) ? 1 : 0;
    const ushort_t* hu = (const ushort_t*)hptr;
    int bf = 1;
    for (int i = 0; i < 512; i += 2) {
        uint_t ex = (hu[i] >> 7) & 0xFFu;
        if (ex > 0x8Cu) bf = 0;  // |v| >= ~1e4 -> not bf16 data
    }
    flags[1] = bf;
}

// M[l][h][d] = sum_c lin_edge_W[l, h*64+c, d] * att_edge[l, h, c]
__global__ void precompute_M(const void* __restrict__ lin_edge_W,
                             const void* __restrict__ att_edge,
                             float* __restrict__ Mbuf, const int* __restrict__ flags) {
    int isbf = flags[1];
    int tid = threadIdx.x;  // 512: l=tid>>8, h=(tid>>6)&3, c=tid&63
    int l = tid >> 8;
    int hc = tid & 255;
    float ae = ldx(att_edge, l * 256 + hc, isbf);
    size_t base = ((size_t)l * 256 + hc) * 3;
    float p0 = ae * ldx(lin_edge_W, base + 0, isbf);
    float p1 = ae * ldx(lin_edge_W, base + 1, isbf);
    float p2 = ae * ldx(lin_edge_W, base + 2, isbf);
    for (int off = 32; off > 0; off >>= 1) {
        p0 += __shfl_down(p0, off);
        p1 += __shfl_down(p1, off);
        p2 += __shfl_down(p2, off);
    }
    if ((tid & 63) == 0) {
        int h = (tid >> 6) & 3;
        Mbuf[(l * 4 + h) * 3 + 0] = p0;
        Mbuf[(l * 4 + h) * 3 + 1] = p1;
        Mbuf[(l * 4 + h) * 3 + 2] = p2;
    }
}

// W_ext[l][272][64] bf16: rows 0..255 = lin_W rows; 256..259 = u_src[h];
// 260..263 = u_dst[h]; 264..271 = 0.  u_src[h][d] = sum_c W[h*64+c][d]*att_src[h][c]
__global__ void precompute_W(const void* __restrict__ lin_W,
                             const void* __restrict__ att_src,
                             const void* __restrict__ att_dst,
                             ushort_t* __restrict__ wext,
                             const int* __restrict__ flags) {
    int isbf = flags[1];
    int idx = blockIdx.x * 256 + threadIdx.x;  // 2*272*64 = 34816
    if (idx >= 2 * 272 * 64) return;
    int d = idx & 63;
    int row = (idx >> 6) % 272;
    int l = idx / (272 * 64);
    float v = 0.f;
    if (row < 256) {
        v = ldx(lin_W, ((size_t)l * 256 + row) * 64 + d, isbf);
    } else if (row < 264) {
        int h = (row - 256) & 3;
        const void* att = (row < 260) ? att_src : att_dst;
        for (int c = 0; c < 64; ++c) {
            v += ldx(lin_W, ((size_t)l * 256 + h * 64 + c) * 64 + d, isbf) *
                 ldx(att, l * 256 + h * 64 + c, isbf);
        }
    }
    wext[((size_t)l * 272 + row) * 64 + d] = f2bf(v);
}

// ---------------- CSR build (once per launch; graph static across layers) ----

// histogram + per-edge slot in one pass
__global__ void csr_hist_pos(const int* __restrict__ ei, int* __restrict__ deg,
                             int* __restrict__ pos, const int* __restrict__ flags) {
    int e = blockIdx.x * 256 + threadIdx.x;
    if (e >= NE) return;
    pos[e] = atomicAdd(&deg[ld_dst(ei, e, flags[0])], 1);
}

// block-level exclusive scan of deg -> rowptr; per-block totals -> bsum
__global__ __launch_bounds__(1024) void csr_scan1(const int* __restrict__ deg,
                                                  int* __restrict__ rowptr,
                                                  int* __restrict__ bsum) {
    __shared__ int sh[1024];
    int i = blockIdx.x * 1024 + threadIdx.x;
    int v = (i < NN) ? deg[i] : 0;
    sh[threadIdx.x] = v;
    __syncthreads();
    for (int off = 1; off < 1024; off <<= 1) {
        int t = (threadIdx.x >= off) ? sh[threadIdx.x - off] : 0;
        __syncthreads();
        sh[threadIdx.x] += t;
        __syncthreads();
    }
    if (i < NN) rowptr[i] = sh[threadIdx.x] - v;
    if (threadIdx.x == 1023) bsum[blockIdx.x] = sh[1023];
}

__global__ void csr_scan2(int* __restrict__ bsum, int nb) {
    if (threadIdx.x != 0) return;
    int run = 0;
    for (int b = 0; b < nb; ++b) {
        int t = bsum[b];
        bsum[b] = run;
        run += t;
    }
}

__global__ __launch_bounds__(1024) void csr_scan3(int* __restrict__ rowptr,
                                                  const int* __restrict__ bsum) {
    int i = blockIdx.x * 1024 + threadIdx.x;
    if (i < NN) rowptr[i] += bsum[blockIdx.x];
    if (i == 0) rowptr[NN] = NE;
}

// edata[slot] = {ea0, ea1, ea2, src-as-bits}, slot grouped by dst
__global__ void csr_fill(const int* __restrict__ ei, const void* __restrict__ edge_attr,
                         const int* __restrict__ rowptr, const int* __restrict__ pos,
                         float4* __restrict__ edata, const int* __restrict__ flags) {
    int e = blockIdx.x * 256 + threadIdx.x;
    if (e >= NE) return;
    int f64 = flags[0], isbf = flags[1];
    int s = ld_src(ei, e, f64), d = ld_dst(ei, e, f64);
    float4 ed;
    ed.x = ldx(edge_attr, (size_t)e * 3 + 0, isbf);
    ed.y = ldx(edge_attr, (size_t)e * 3 + 1, isbf);
    ed.z = ldx(edge_attr, (size_t)e * 3 + 2, isbf);
    ed.w = __int_as_float(s);
    edata[rowptr[d] + pos[e]] = ed;
}

// ---------------- per-layer kernels ----------------------------------------

// ONE WAVE PER BLOCK (16 nodes), 3125 blocks -> ~12 co-resident blocks/CU for
// latency hiding. bf16 path: MFMA GEMM (a=wext row, b=z row; each lane owns
// one node col and 4 wcols/tile), LDS-staged transform, coalesced 8B stores.
// Cols 256..263 of the extended GEMM give a_src/a_dst directly.
__global__ __launch_bounds__(64) void node_linear(
    const void* __restrict__ h_in,   // layer 0 input
    const void* __restrict__ zprev,  // layer>0 input (bf16 if isbf else f32)
    const void* __restrict__ lin_W,
    const void* __restrict__ att_src, const void* __restrict__ att_dst,
    const ushort_t* __restrict__ wext,  // L*272*64 bf16
    ushort_t* __restrict__ xb,          // N*256 bf16, [n][c*4+h]
    float* __restrict__ a_src, float* __restrict__ a_dst,
    const int* __restrict__ flags, int layer) {
    __shared__ __align__(16) char smem[16 * SROW * 2];  // 8448 B
    int isbf = flags[1];
    int lane = threadIdx.x;  // single wave
    int mbase = blockIdx.x * 16;
    if (isbf) {
        int q = lane >> 4, mi = lane & 15;
        int mynode = mbase + mi;  // always < NN (50000 = 3125*16)
        const ushort_t* zrow = (layer == 0)
            ? (const ushort_t*)h_in + (size_t)mynode * 64
            : (const ushort_t*)zprev + (size_t)mynode * 64;
        bf16x8 b0 = *(const bf16x8*)(zrow + q * 8);
        bf16x8 b1 = *(const bf16x8*)(zrow + 32 + q * 8);
        const ushort_t* wl = wext + (size_t)layer * 272 * 64;
        ushort_t* st = (ushort_t*)smem;
        for (int t = 0; t < 17; ++t) {
            const ushort_t* wrow = wl + (size_t)(t * 16 + mi) * 64;
            bf16x8 a0 = *(const bf16x8*)(wrow + q * 8);
            bf16x8 a1 = *(const bf16x8*)(wrow + 32 + q * 8);
            f32x4 acc = {0.f, 0.f, 0.f, 0.f};
            // D col=lane&15 -> node, row=q*4+r -> wcol (verified r7)
            acc = __builtin_amdgcn_mfma_f32_16x16x32_bf16(a0, b0, acc, 0, 0, 0);
            acc = __builtin_amdgcn_mfma_f32_16x16x32_bf16(a1, b1, acc, 0, 0, 0);
            if (t < 16) {
                ushort4 pk;
                pk.x = f2bf(acc[0]);
                pk.y = f2bf(acc[1]);
                pk.z = f2bf(acc[2]);
                pk.w = f2bf(acc[3]);
                *(ushort4*)(st + mi * SROW + t * 16 + q * 4) = pk;
            } else {
#pragma unroll
                for (int r = 0; r < 4; ++r) {
                    int jj = q * 4 + r;
                    if (jj < 4) a_src[mynode * 4 + jj] = acc[r];
                    else if (jj < 8) a_dst[mynode * 4 + (jj - 4)] = acc[r];
                }
            }
        }
        // transform: [node][h*64+c] (LDS) -> xb[node][c*4+h] (global), coalesced
        for (int nn = 0; nn < 16; ++nn) {
            int node = mbase + nn;
            ushort4 pk;
            pk.x = st[nn * SROW + lane];
            pk.y = st[nn * SROW + 64 + lane];
            pk.z = st[nn * SROW + 128 + lane];
            pk.w = st[nn * SROW + 192 + lane];
            *(ushort4*)(xb + (size_t)node * 256 + lane * 4) = pk;
        }
        return;
    }
    // ---- f32 fallback (dead in practice; correctness only) ----
    float* zsh = (float*)smem;  // 16*64 f32 = 4096 B
    for (int i = lane; i < 16 * 64; i += 64) {
        zsh[i] = (layer == 0) ? ((const float*)h_in)[(size_t)mbase * 64 + i]
                              : ((const float*)zprev)[(size_t)mbase * 64 + i];
    }
    __syncthreads();
    for (int chunk = 0; chunk < 4; ++chunk) {
        int o = chunk * 64 + lane;  // output channel; head = chunk, c = lane
        const float* wr = (const float*)lin_W + ((size_t)layer * 256 + o) * 64;
        float ats = ((const float*)att_src)[layer * 256 + o];
        float atd = ((const float*)att_dst)[layer * 256 + o];
        for (int nn = 0; nn < 16; ++nn) {
            float acc = 0.f;
            for (int k = 0; k < 64; ++k) acc += zsh[nn * 64 + k] * wr[k];
            int n = mbase + nn;
            xb[(size_t)n * 256 + lane * 4 + chunk] = f2bf(acc);
            float ps = acc * ats, pd = acc * atd;
            for (int off = 32; off > 0; off >>= 1) {
                ps += __shfl_down(ps, off);
                pd += __shfl_down(pd, off);
            }
            if (lane == 0) {
                a_src[n * 4 + chunk] = ps;
                a_dst[n * 4 + chunk] = pd;
            }
        }
    }
}

// One wave per node: softmax-weighted neighbor aggregation. Per 64-edge chunk,
// active lanes compute (ex0..3, src) once into wave-private LDS; the j-loop
// uses broadcast ds_reads (replaces 5 shuffles/edge) and every lane
// accumulates denominators redundantly (no den shuffles). Then head-mean +
// bias, LayerNorm, SiLU.
__global__ __launch_bounds__(256) void node_aggregate(
    const int* __restrict__ rowptr, const float4* __restrict__ edata,
    const float* __restrict__ a_src, const float* __restrict__ a_dst,
    const ushort_t* __restrict__ xb, const float* __restrict__ Mbuf,
    const void* __restrict__ bias, const void* __restrict__ gamma,
    const void* __restrict__ beta, void* __restrict__ zout,
    void* __restrict__ outp, const int* __restrict__ flags, int layer, int last) {
    __shared__ float4 wsh[4][64];
    __shared__ int ssh[4][64];
    int isbf = flags[1];
    int wv = threadIdx.x >> 6;
    int lane = threadIdx.x & 63;
    int n = blockIdx.x * 4 + wv;
    float M[12];
#pragma unroll
    for (int i = 0; i < 12; ++i) M[i] = Mbuf[layer * 12 + i];
    float4 ad = *(const float4*)(a_dst + (size_t)n * 4);
    int start = rowptr[n], end = rowptr[n + 1];
    float acc0 = 0.f, acc1 = 0.f, acc2 = 0.f, acc3 = 0.f;
    float den0 = 0.f, den1 = 0.f, den2 = 0.f, den3 = 0.f;
    for (int cb = start; cb < end; cb += 64) {
        int m = end - cb;
        if (m > 64) m = 64;
        if (lane < m) {
            float4 ed = edata[cb + lane];
            int s = __float_as_int(ed.w);
            float4 as4 = *(const float4*)(a_src + (size_t)s * 4);
            float t0 = as4.x + ad.x + ed.x * M[0] + ed.y * M[1] + ed.z * M[2];
            float t1 = as4.y + ad.y + ed.x * M[3] + ed.y * M[4] + ed.z * M[5];
            float t2 = as4.z + ad.z + ed.x * M[6] + ed.y * M[7] + ed.z * M[8];
            float t3 = as4.w + ad.w + ed.x * M[9] + ed.y * M[10] + ed.z * M[11];
            t0 = t0 > 0.f ? t0 : NEG_SLOPE * t0;
            t1 = t1 > 0.f ? t1 : NEG_SLOPE * t1;
            t2 = t2 > 0.f ? t2 : NEG_SLOPE * t2;
            t3 = t3 > 0.f ? t3 : NEG_SLOPE * t3;
            float4 ex;
            ex.x = __expf(fminf(t0, 80.f));
            ex.y = __expf(fminf(t1, 80.f));
            ex.z = __expf(fminf(t2, 80.f));
            ex.w = __expf(fminf(t3, 80.f));
            wsh[wv][lane] = ex;
            ssh[wv][lane] = s;
        }
        // same-wave LDS write->read: DS pipe is in-order per wave; compiler
        // inserts lgkmcnt for the may-alias dependency.
        for (int j = 0; j < m; ++j) {
            float4 wj = wsh[wv][j];       // broadcast read
            int sj = ssh[wv][j];          // broadcast read
            ushort4 xv = *(const ushort4*)(xb + (size_t)sj * 256 + lane * 4);
            acc0 += wj.x * bf2f(xv.x);
            acc1 += wj.y * bf2f(xv.y);
            acc2 += wj.z * bf2f(xv.z);
            acc3 += wj.w * bf2f(xv.w);
            den0 += wj.x; den1 += wj.y; den2 += wj.z; den3 += wj.w;
        }
    }
    float v = ldx(bias, layer * 64 + lane, isbf) +
              0.25f * (acc0 / (den0 + 1e-16f) + acc1 / (den1 + 1e-16f) +
                       acc2 / (den2 + 1e-16f) + acc3 / (den3 + 1e-16f));
    float sum = v;
    for (int off = 1; off < 64; off <<= 1) sum += __shfl_xor(sum, off);
    float mu = sum * (1.f / 64.f);
    float d = v - mu;
    float vv = d * d;
    for (int off = 1; off < 64; off <<= 1) vv += __shfl_xor(vv, off);
    float var = vv * (1.f / 64.f);
    float ln = d * rsqrtf(var + LN_EPS) * ldx(gamma, layer * 64 + lane, isbf) +
               ldx(beta, layer * 64 + lane, isbf);
    float sl = ln / (1.f + __expf(-ln));
    size_t idx = (size_t)n * 64 + lane;
    if (last) {
        if (isbf) ((ushort_t*)outp)[idx] = f2bf(sl);
        else      ((float*)outp)[idx] = sl;
    } else {
        if (isbf) ((ushort_t*)zout)[idx] = f2bf(sl);
        else      ((float*)zout)[idx] = sl;
    }
}

extern "C" void kernel_launch(void* const* d_in, const int* in_sizes, int n_in,
                              void* d_out, int out_size, void* d_ws, size_t ws_size,
                              hipStream_t stream) {
    int off = (in_sizes[0] == 1) ? 1 : 0;
    const void* h_in  = d_in[off + 0];
    const int*  ei    = (const int*)d_in[off + 1];
    const void* eattr = d_in[off + 2];
    const void* linW  = d_in[off + 3];
    const void* linEW = d_in[off + 4];
    const void* attS  = d_in[off + 5];
    const void* attD  = d_in[off + 6];
    const void* attE  = d_in[off + 7];
    const void* bias  = d_in[off + 8];
    const void* gamma = d_in[off + 9];
    const void* beta  = d_in[off + 10];

    // bump allocator, 256 B aligned (~56.5 MB total)
    char* w = (char*)d_ws;
    size_t o = 0;
    auto alloc = [&](size_t bytes) {
        void* p = w + o;
        o += (bytes + 255) & ~(size_t)255;
        return p;
    };
    int*    flags  = (int*)alloc(8);
    float*  Mbuf   = (float*)alloc(24 * 4);
    ushort_t* wext = (ushort_t*)alloc((size_t)2 * 272 * 64 * 2);
    float*  a_src  = (float*)alloc((size_t)NN * 4 * 4);
    float*  a_dst  = (float*)alloc((size_t)NN * 4 * 4);
    int*    rowptr = (int*)alloc((size_t)(NN + 1) * 4);
    int*    deg    = (int*)alloc((size_t)NN * 4);
    int*    pos    = (int*)alloc((size_t)NE * 4);
    int*    bsum   = (int*)alloc(64 * 4);
    void*   zbuf   = alloc((size_t)NN * 64 * 4);  // f32-sized; bf16 when isbf
    ushort_t* xb   = (ushort_t*)alloc((size_t)NN * 256 * 2);
    float4* edata  = (float4*)alloc((size_t)NE * 16);

    detect_flags<<<1, 64, 0, stream>>>(ei, h_in, flags);
    precompute_M<<<1, 512, 0, stream>>>(linEW, attE, Mbuf, flags);
    precompute_W<<<136, 256, 0, stream>>>(linW, attS, attD, wext, flags);
    int nb = (NN + 1023) / 1024;  // 49
    hipMemsetAsync(deg, 0, (size_t)NN * 4, stream);
    csr_hist_pos<<<(NE + 255) / 256, 256, 0, stream>>>(ei, deg, pos, flags);
    csr_scan1<<<nb, 1024, 0, stream>>>(deg, rowptr, bsum);
    csr_scan2<<<1, 64, 0, stream>>>(bsum, nb);
    csr_scan3<<<nb, 1024, 0, stream>>>(rowptr, bsum);
    csr_fill<<<(NE + 255) / 256, 256, 0, stream>>>(ei, eattr, rowptr, pos, edata, flags);

    for (int l = 0; l < 2; ++l) {
        node_linear<<<NN / 16, 64, 0, stream>>>(h_in, zbuf, linW, attS, attD, wext,
                                                xb, a_src, a_dst, flags, l);
        node_aggregate<<<NN / 4, 256, 0, stream>>>(rowptr, edata, a_src, a_dst,
                                                   xb, Mbuf, bias, gamma, beta,
                                                   zbuf, d_out, flags, l, l == 1);
    }
}